// Round 7
// baseline (1593.325 us; speedup 1.0000x reference)
//
#include <hip/hip_runtime.h>

typedef unsigned short u16;
typedef unsigned int u32;
typedef unsigned long long u64;
typedef __attribute__((ext_vector_type(8))) short short8;
typedef __attribute__((ext_vector_type(4))) float floatx4;

#define B_ 16
#define S_ 64
#define H_ 512
#define V_ 32000
#define G3 1536   // 3*H
#define TD 63     // T-1
#define MROWS 1008
#define NBLK 16   // rec_kernel blocks (one per 32-col slice of h)
#define NTILES 250 // 32000/128 n-tiles in the logits GEMM

__device__ __forceinline__ float b2f(u16 u) {
  union { u32 i; float f; } c; c.i = ((u32)u) << 16; return c.f;
}
__device__ __forceinline__ u16 f2b(float f) {
  union { float f; u32 i; } c; c.f = f;
  u32 u = c.i;
  return (u16)((u + 0x7FFFu + ((u >> 16) & 1u)) >> 16);  // RNE
}
__device__ __forceinline__ short8 pack8(float4 a, float4 b) {
  short8 r;
  r[0] = (short)f2b(a.x); r[1] = (short)f2b(a.y); r[2] = (short)f2b(a.z); r[3] = (short)f2b(a.w);
  r[4] = (short)f2b(b.x); r[5] = (short)f2b(b.y); r[6] = (short)f2b(b.z); r[7] = (short)f2b(b.w);
  return r;
}

// coherent (MALL) 8-bf16 load via two relaxed agent-scope u64 atomics
__device__ __forceinline__ short8 ld_bf8_coh(const u16* p) {
  u64 a = __hip_atomic_load((const u64*)p, __ATOMIC_RELAXED, __HIP_MEMORY_SCOPE_AGENT);
  u64 b = __hip_atomic_load((const u64*)(p + 4), __ATOMIC_RELAXED, __HIP_MEMORY_SCOPE_AGENT);
  union { u64 q[2]; short8 s; } u; u.q[0] = a; u.q[1] = b; return u.s;
}

// ---------------- embedding gather (f32 -> bf16) ----------------
__global__ void __launch_bounds__(256) gather_kernel(
    const int* __restrict__ x, const int* __restrict__ y,
    const float* __restrict__ emb_enc, const float* __restrict__ emb_dec,
    u16* __restrict__ ex, u16* __restrict__ ey)
{
  const int r = blockIdx.x, tid = threadIdx.x;
  if (r < B_ * S_) {                       // encoder row m = b*64+s
    int tok = x[r];
    float2 v = ((const float2*)(emb_enc + (size_t)tok * H_))[tid];
    ((u32*)(ex + (size_t)r * H_))[tid] = (u32)f2b(v.x) | ((u32)f2b(v.y) << 16);
  } else {                                 // decoder row m = t*16+b
    int m = r - B_ * S_;
    int t = m >> 4, b = m & 15;
    int tok = y[b * 64 + t];
    float2 v = ((const float2*)(emb_dec + (size_t)tok * H_))[tid];
    ((u32*)(ey + (size_t)m * H_))[tid] = (u32)f2b(v.x) | ((u32)f2b(v.y) << 16);
  }
}

// ---------------- bf16-MFMA GEMM: C = A @ B^T + bias ----------------
// A:[M,K] bf16, B:[N,K] f32 (converted to bf16 while staging), bias f32[N]
// MODE 0: C fp32 [M,N].
// MODE 1: C fp32 into d_out, row remap m=t*16+b -> (b*63+t), PLUS fused
//         per-row online softmax partials (prtl) + target-token logit (tokv).
// MODE 2: C = tanh(.) -> bf16 [M,N]
// SWAP 1: blockIdx.x indexes M-tiles, blockIdx.y indexes N-tiles.
template <int MODE, int SWAP = 0>
__global__ void __launch_bounds__(256) gemm_bt(
    const u16* __restrict__ A, const float* __restrict__ Bm,
    const float* __restrict__ bias, void* __restrict__ Cout, int M, int N, int K,
    float* __restrict__ prtl, float* __restrict__ tokv, const int* __restrict__ yarr)
{
  __shared__ u16 As[64 * 40];
  __shared__ u16 Bs[128 * 40];
  const int tid = threadIdx.x;
  const int wave = tid >> 6, lane = tid & 63;
  const int l15 = lane & 15, quad = lane >> 4;
  const int m0 = (SWAP ? blockIdx.x : blockIdx.y) * 64;
  const int n0 = (SWAP ? blockIdx.y : blockIdx.x) * 128;
  floatx4 acc[4][2] = {};

  for (int kk = 0; kk < K; kk += 32) {
    {
      int row = tid >> 2, ch = tid & 3;
      short8 v = {};
      int gm = m0 + row;
      if (gm < M) v = *(const short8*)(A + (size_t)gm * K + kk + ch * 8);
      *(short8*)(As + row * 40 + ch * 8) = v;
    }
#pragma unroll
    for (int i = 0; i < 4; ++i) {
      int idx2 = tid + i * 256;
      int row = idx2 >> 3, c4 = idx2 & 7;
      int gn = n0 + row;
      float4 w = *(const float4*)(Bm + (size_t)gn * K + kk + c4 * 4);
      uint2 p;
      p.x = (u32)f2b(w.x) | ((u32)f2b(w.y) << 16);
      p.y = (u32)f2b(w.z) | ((u32)f2b(w.w) << 16);
      *(uint2*)(Bs + row * 40 + c4 * 4) = p;
    }
    __syncthreads();
    short8 af[4], bfr[2];
#pragma unroll
    for (int mt = 0; mt < 4; ++mt)
      af[mt] = *(const short8*)(As + (mt * 16 + l15) * 40 + quad * 8);
#pragma unroll
    for (int nt = 0; nt < 2; ++nt)
      bfr[nt] = *(const short8*)(Bs + (wave * 32 + nt * 16 + l15) * 40 + quad * 8);
#pragma unroll
    for (int mt = 0; mt < 4; ++mt)
#pragma unroll
      for (int nt = 0; nt < 2; ++nt)
        acc[mt][nt] = __builtin_amdgcn_mfma_f32_16x16x32_bf16(af[mt], bfr[nt], acc[mt][nt], 0, 0, 0);
    __syncthreads();
  }

  if (MODE == 1) {
    // logits write + fused per-row online softmax partial over this block's 128 cols
    __shared__ float2 red[4][64];
    const int y0 = n0 >> 7;
#pragma unroll
    for (int mt = 0; mt < 4; ++mt) {
#pragma unroll
      for (int r = 0; r < 4; ++r) {
        const int gm = m0 + mt * 16 + quad * 4 + r;
        const int gn0 = n0 + wave * 32 + l15;
        float vv0 = acc[mt][0][r] + bias[gn0];
        float vv1 = acc[mt][1][r] + bias[gn0 + 16];
        if (gm < M) {
          const int tt = gm >> 4, bb = gm & 15;
          float* orow = (float*)Cout + ((size_t)bb * TD + tt) * V_;
          orow[gn0] = vv0;
          orow[gn0 + 16] = vv1;
          const int tok = yarr[bb * 64 + tt + 1];
          if (tok == gn0) tokv[gm] = vv0;
          if (tok == gn0 + 16) tokv[gm] = vv1;
        }
        float mx = fmaxf(vv0, vv1);
        float sm = __expf(vv0 - mx) + __expf(vv1 - mx);
#pragma unroll
        for (int d = 1; d < 16; d <<= 1) {
          const float om = __shfl_xor(mx, d), os = __shfl_xor(sm, d);
          const float nm = fmaxf(mx, om);
          sm = sm * __expf(mx - nm) + os * __expf(om - nm);
          mx = nm;
        }
        if (l15 == 0) red[wave][mt * 16 + quad * 4 + r] = make_float2(mx, sm);
      }
    }
    __syncthreads();
    if (tid < 64) {
      const float2 p0 = red[0][tid], p1 = red[1][tid], p2 = red[2][tid], p3 = red[3][tid];
      float M2 = fmaxf(fmaxf(p0.x, p1.x), fmaxf(p2.x, p3.x));
      float S2 = p0.y * __expf(p0.x - M2) + p1.y * __expf(p1.x - M2)
               + p2.y * __expf(p2.x - M2) + p3.y * __expf(p3.x - M2);
      const int gm = m0 + tid;
      if (gm < M) {
        float* pp = prtl + ((size_t)gm * NTILES + y0) * 2;
        pp[0] = M2; pp[1] = S2;
      }
    }
  } else {
#pragma unroll
    for (int mt = 0; mt < 4; ++mt) {
#pragma unroll
      for (int nt = 0; nt < 2; ++nt) {
        int gn = n0 + wave * 32 + nt * 16 + l15;
        float bv = bias[gn];
#pragma unroll
        for (int r = 0; r < 4; ++r) {
          int gm = m0 + mt * 16 + quad * 4 + r;  // C/D: col=lane&15, row=quad*4+reg
          if (gm < M) {
            float v = acc[mt][nt][r] + bv;
            if (MODE == 0) {
              ((float*)Cout)[(size_t)gm * N + gn] = v;
            } else {
              ((u16*)Cout)[(size_t)gm * N + gn] = f2b(tanhf(v));
            }
          }
        }
      }
    }
  }
}

// ---------------- cooperative recurrence (GRU chain ONLY) ----------------
// 16 blocks x 384 threads; block k owns h-columns [32k, 32k+32).
// FENCE-FREE sync: all cross-block-live data (ha h-exchange + 32 signal slots)
// uses relaxed agent-scope atomics (MALL-coherent, bypass non-coherent L2s).
// Producer order: h' atomic stores -> s_waitcnt vmcnt(0) -> own-slot signal
// (waves 2 & 5 each own one slot). Consumers poll all 32 slots (monotone
// generation counters). No per-phase L2 writeback/invalidate; gi stays L2-cached.
// eo/hcat are plain stores (consumed only by later kernels; kernel-end flush).
struct RecArgs {
  const float* gi_enc;   // [1024][1536]  row = b*64+s
  const float* gi_dec;   // [1008][1536]  row = t*16+b
  const float* Whe;      // [1536][512] raw W_hh_e
  const float* Whd;      // [1536][512] raw W_hh_d
  const float* bhe;      // [1536]
  const float* bhd;      // [1536]
  u16* eo;               // enc_out bf16 [16][64][512]
  u16* ha;               // [2][16][512] bf16 h exchange (MALL atomics)
  u16* hcat;             // [1008][1024] bf16: cols 0..511 = h_t, 512..1023 = attn (later)
  int* bar;              // 32 signal slots (block*2 + half), stride 32 ints (128 B)
};

__device__ __forceinline__ void pollbar(int* slots, int lane, int gen) {
  while (__hip_atomic_load(slots + (lane & 31) * 32, __ATOMIC_RELAXED, __HIP_MEMORY_SCOPE_AGENT) < gen) {}
  asm volatile("" ::: "memory");
}

// One GRU gate+update phase. p = read parity (reads ha[p], writes ha[p^1]).
template <int ISENC>
__device__ __forceinline__ void gate_phase(const RecArgs& a, int wave, int lane, int l15, int quad,
    int J, int step, int p, const short8* wf, float bh, float* hreg,
    float (&lds_rz)[2][2][16][16], int signal_gen, bool do_signal)
{
  const int sub = wave % 3, half = wave / 3;
  const int jc = J + half * 16 + l15;
  const float* gi = ISENC ? a.gi_enc : a.gi_dec;
  float giv[4];
#pragma unroll
  for (int r = 0; r < 4; ++r) {
    const int b = quad * 4 + r;
    const int row = ISENC ? (b * 64 + step) : (step * 16 + b);
    giv[r] = gi[(size_t)row * G3 + sub * 512 + jc];
  }
  const u16* hb = a.ha + p * 8192 + l15 * 512 + quad * 8;
  short8 af[16];
#pragma unroll
  for (int kk = 0; kk < 16; ++kk) af[kk] = ld_bf8_coh(hb + kk * 32);
  floatx4 acc = {0.f, 0.f, 0.f, 0.f};
#pragma unroll
  for (int kk = 0; kk < 16; ++kk)
    acc = __builtin_amdgcn_mfma_f32_16x16x32_bf16(af[kk], wf[(ISENC ? 0 : 16) + kk], acc, 0, 0, 0);
  if (sub < 2) {
#pragma unroll
    for (int r = 0; r < 4; ++r)
      lds_rz[sub][half][quad * 4 + r][l15] = acc[r] + bh + giv[r];
    __syncthreads();
  } else {
    __syncthreads();
    const int pn = p ^ 1;
#pragma unroll
    for (int r = 0; r < 4; ++r) {
      const int b = quad * 4 + r;
      const float rp = lds_rz[0][half][b][l15];
      const float zp = lds_rz[1][half][b][l15];
      const float rr = 1.f / (1.f + __expf(-rp));
      const float zz = 1.f / (1.f + __expf(-zp));
      const float nn = tanhf(giv[r] + rr * (acc[r] + bh));   // n = tanh(gi_n + r*(gh_n + bhh_n))
      const float hv = (1.f - zz) * nn + zz * hreg[r];
      hreg[r] = hv;
      const u16 h16 = f2b(hv);
      const u32 up = (u32)h16 | ((u32)(u16)__shfl_xor((int)h16, 1) << 16);
      if (!(lane & 1)) {
        __hip_atomic_store((u32*)(a.ha + pn * 8192 + b * 512 + jc), up,
                           __ATOMIC_RELAXED, __HIP_MEMORY_SCOPE_AGENT);
        if (ISENC) *(u32*)(a.eo + ((size_t)(b * 64 + step)) * 512 + jc) = up;
        else       *(u32*)(a.hcat + ((size_t)(step * 16 + b)) * 1024 + jc) = up;
      }
    }
    if (do_signal) {
      asm volatile("s_waitcnt vmcnt(0)" ::: "memory");     // h' stores at MALL
      if (lane == 0)
        __hip_atomic_store(a.bar + ((int)blockIdx.x * 2 + half) * 32, signal_gen,
                           __ATOMIC_RELAXED, __HIP_MEMORY_SCOPE_AGENT);
    }
  }
}

__global__ void __launch_bounds__(384) rec_kernel(RecArgs a) {
  __shared__ float lds_rz[2][2][16][16];
  const int tid = threadIdx.x;
  const int wave = tid >> 6, lane = tid & 63;
  const int l15 = lane & 15, quad = lane >> 4;
  const int J = blockIdx.x * 32;
  const int sub = wave % 3, half = wave / 3;

  // ---- one-time: stage W_hh gate fragments into registers (bf16) ----
  short8 wf[32];
  const int row = sub * 512 + J + half * 16 + l15;   // gate row of W_hh
  const float* pe = a.Whe + (size_t)row * 512 + quad * 8;
  const float* pd = a.Whd + (size_t)row * 512 + quad * 8;
#pragma unroll
  for (int kk = 0; kk < 16; ++kk) {
    wf[kk]      = pack8(*(const float4*)(pe + kk * 32), *(const float4*)(pe + kk * 32 + 4));
    wf[16 + kk] = pack8(*(const float4*)(pd + kk * 32), *(const float4*)(pd + kk * 32 + 4));
  }
  const int jc = J + half * 16 + l15;
  const float bhe = a.bhe[sub * 512 + jc];
  const float bhd = a.bhd[sub * 512 + jc];

  float hreg[4] = {0.f, 0.f, 0.f, 0.f};

  // ---- init: zero h buffer 0 (atomic stores), then signal gen=1 ----
  if (sub == 2) {
    if (!(lane & 1)) {
#pragma unroll
      for (int r = 0; r < 4; ++r)
        __hip_atomic_store((u32*)(a.ha + (quad * 4 + r) * 512 + jc), 0u,
                           __ATOMIC_RELAXED, __HIP_MEMORY_SCOPE_AGENT);
    }
    asm volatile("s_waitcnt vmcnt(0)" ::: "memory");
    if (lane == 0)
      __hip_atomic_store(a.bar + ((int)blockIdx.x * 2 + half) * 32, 1,
                         __ATOMIC_RELAXED, __HIP_MEMORY_SCOPE_AGENT);
  }

  int gen = 1;
  // ---- encoder ----
  for (int s = 0; s < S_; ++s) {
    pollbar(a.bar, lane, gen);
    gate_phase<1>(a, wave, lane, l15, quad, J, s, s & 1, wf, bhe, hreg, lds_rz, gen + 1, true);
    ++gen;
  }
  // ---- decoder (no signal after the last step) ----
  for (int t = 0; t < TD; ++t) {
    pollbar(a.bar, lane, gen);
    gate_phase<0>(a, wave, lane, l15, quad, J, t, t & 1, wf, bhd, hreg, lds_rz, gen + 1, t < TD - 1);
    ++gen;
  }
}

// ---------------- attention, hoisted out of the loop ----------------
__global__ void __launch_bounds__(512) attn_kernel(
    const u16* __restrict__ eo16, u16* __restrict__ hcat)
{
  __shared__ float sc[64][9];
  __shared__ float wts[64];
  const int m = blockIdx.x, b = m & 15;
  const int tid = threadIdx.x;
  const u16* eo = eo16 + (size_t)b * 64 * 512;
  const u16* h = hcat + (size_t)m * 1024;
  {
    const int s = tid >> 3, q = tid & 7;
    const u16* ep = eo + s * 512 + q * 64;
    const u16* hp = h + q * 64;
    float acc = 0.f;
#pragma unroll
    for (int u = 0; u < 8; ++u) {
      short8 e8 = *(const short8*)(ep + u * 8);
      short8 h8 = *(const short8*)(hp + u * 8);
#pragma unroll
      for (int i = 0; i < 8; ++i) acc += b2f((u16)e8[i]) * b2f((u16)h8[i]);
    }
    sc[s][q] = acc;
  }
  __syncthreads();
  if (tid < 64) {
    float v = 0.f;
#pragma unroll
    for (int u = 0; u < 8; ++u) v += sc[tid][u];
    float mx = v;
#pragma unroll
    for (int d = 1; d < 64; d <<= 1) mx = fmaxf(mx, __shfl_xor(mx, d));
    float e = __expf(v - mx);
    float sum = e;
#pragma unroll
    for (int d = 1; d < 64; d <<= 1) sum += __shfl_xor(sum, d);
    wts[tid] = e / sum;
  }
  __syncthreads();
  {
    const int j = tid;
    float acc = 0.f;
#pragma unroll 8
    for (int s2 = 0; s2 < 64; ++s2) acc += wts[s2] * b2f(eo[s2 * 512 + j]);
    hcat[(size_t)m * 1024 + 512 + j] = f2b(acc);
  }
}

// ---------------- loss: merge per-tile softmax partials ----------------
__global__ void __launch_bounds__(64) loss_merge_kernel(
    const float* __restrict__ prtl, const float* __restrict__ tokv, float* __restrict__ nll)
{
  const int m = blockIdx.x;
  const int lane = threadIdx.x;
  float mx = -1e30f, sm = 0.f;
  for (int i = lane; i < NTILES; i += 64) {
    const float pm = prtl[((size_t)m * NTILES + i) * 2];
    const float ps = prtl[((size_t)m * NTILES + i) * 2 + 1];
    const float nm = fmaxf(mx, pm);
    sm = sm * __expf(mx - nm) + ps * __expf(pm - nm);
    mx = nm;
  }
#pragma unroll
  for (int d = 1; d < 64; d <<= 1) {
    const float om = __shfl_xor(mx, d), os = __shfl_xor(sm, d);
    const float nm = fmaxf(mx, om);
    sm = sm * __expf(mx - nm) + os * __expf(om - nm);
    mx = nm;
  }
  if (lane == 0) nll[m] = mx + logf(sm) - tokv[m];
}

__global__ void __launch_bounds__(256) loss_final_kernel(const float* __restrict__ nll, float* __restrict__ out) {
  __shared__ float wred[4];
  const int tid = threadIdx.x;
  float s = 0.f;
  for (int i = tid; i < MROWS; i += 256) s += nll[i];
#pragma unroll
  for (int d = 1; d < 64; d <<= 1) s += __shfl_xor(s, d);
  if ((tid & 63) == 0) wred[tid >> 6] = s;
  __syncthreads();
  if (tid == 0) out[0] = (wred[0] + wred[1] + wred[2] + wred[3]) / 1008.f;
}

// ---------------- launch ----------------
extern "C" void kernel_launch(void* const* d_in, const int* in_sizes, int n_in,
                              void* d_out, int out_size, void* d_ws, size_t ws_size,
                              hipStream_t stream)
{
  const int*   x       = (const int*)d_in[0];
  const int*   y       = (const int*)d_in[1];
  const float* emb_enc = (const float*)d_in[2];
  const float* W_ih_e  = (const float*)d_in[3];
  const float* W_hh_e  = (const float*)d_in[4];
  const float* b_ih_e  = (const float*)d_in[5];
  const float* b_hh_e  = (const float*)d_in[6];
  const float* emb_dec = (const float*)d_in[7];
  const float* W_ih_d  = (const float*)d_in[8];
  const float* W_hh_d  = (const float*)d_in[9];
  const float* b_ih_d  = (const float*)d_in[10];
  const float* b_hh_d  = (const float*)d_in[11];
  const float* W_c     = (const float*)d_in[12];
  const float* b_c     = (const float*)d_in[13];
  const float* W_out   = (const float*)d_in[14];
  const float* b_out   = (const float*)d_in[15];

  // ws layout (16,687,040 B total — within the proven footprint)
  char* ws = (char*)d_ws;
  float* gi_enc = (float*)(ws + 0);           //  6,291,456
  float* gi_dec = (float*)(ws + 6291456);     //  6,193,152  -> 12,484,608
  u16* embx     = (u16*)(ws + 12484608);      //  1,048,576  -> 13,533,184 (dead after gi GEMMs)
  u16* emby     = (u16*)(ws + 13533184);      //  1,032,192  -> 14,565,376 (dead after gi GEMMs)
  u16* hcat     = (u16*)(ws + 12484608);      //  2,064,384  -> 14,548,992 (reuses embx/emby region)
  u16* Dm       = (u16*)(ws + 14565376);      //  1,032,192  -> 15,597,568
  u16* eo16     = (u16*)(ws + 15597568);      //  1,048,576  -> 16,646,144
  u16* ha16     = (u16*)(ws + 16646144);      //     32,768  -> 16,678,912
  float* nll    = (float*)(ws + 16678912);    //      4,032  -> 16,682,944
  int* bar      = (int*)(ws + 16682944);      //      4,096  -> 16,687,040
  // gi_enc/gi_dec are DEAD after rec_kernel -> reuse for loss partials:
  float* prtl   = (float*)(ws + 0);           //  2,016,000  (1008 x 250 x 2 f32)
  float* tokv   = (float*)(ws + 2016000);     //      4,032

  hipMemsetAsync(bar, 0, 4096, stream);       // 32 signal slots (graph-capture safe)

  gather_kernel<<<dim3(B_ * S_ + MROWS), dim3(256), 0, stream>>>(x, y, emb_enc, emb_dec, embx, emby);

  gemm_bt<0><<<dim3(12, 16), dim3(256), 0, stream>>>(
      embx, W_ih_e, b_ih_e, (void*)gi_enc, 1024, G3, 512, nullptr, nullptr, nullptr);
  gemm_bt<0><<<dim3(12, 16), dim3(256), 0, stream>>>(
      emby, W_ih_d, b_ih_d, (void*)gi_dec, MROWS, G3, 512, nullptr, nullptr, nullptr);

  RecArgs ra{gi_enc, gi_dec, W_hh_e, W_hh_d, b_hh_e, b_hh_d, eo16, ha16, hcat, bar};
  rec_kernel<<<dim3(NBLK), dim3(384), 0, stream>>>(ra);

  attn_kernel<<<dim3(MROWS), dim3(512), 0, stream>>>(eo16, hcat);

  // Dm = tanh([h;attn] @ W_c^T + b_c)  (bf16 out)
  gemm_bt<2><<<dim3(4, 16), dim3(256), 0, stream>>>(
      hcat, W_c, b_c, (void*)Dm, MROWS, 512, 1024, nullptr, nullptr, nullptr);

  // logits + fused per-row softmax partials (SWAP grid: m-tiles fast for B-panel L2 reuse)
  gemm_bt<1, 1><<<dim3(16, NTILES), dim3(256), 0, stream>>>(
      Dm, W_out, b_out, d_out, MROWS, V_, 512, prtl, tokv, y);

  loss_merge_kernel<<<dim3(MROWS), dim3(64), 0, stream>>>(prtl, tokv, nll);
  loss_final_kernel<<<dim3(1), dim3(256), 0, stream>>>(nll, ((float*)d_out) + (size_t)MROWS * V_);
}

// Round 8
// 1279.581 us; speedup vs baseline: 1.2452x; 1.2452x over previous
//
#include <hip/hip_runtime.h>

typedef unsigned short u16;
typedef unsigned int u32;
typedef __attribute__((ext_vector_type(8))) short short8;
typedef __attribute__((ext_vector_type(4))) float floatx4;

#define B_ 16
#define S_ 64
#define H_ 512
#define V_ 32000
#define G3 1536   // 3*H
#define TD 63     // T-1
#define MROWS 1008
#define NBLK 16   // rec_kernel blocks (one per 32-col slice of h)

__device__ __forceinline__ float b2f(u16 u) {
  union { u32 i; float f; } c; c.i = ((u32)u) << 16; return c.f;
}
__device__ __forceinline__ u16 f2b(float f) {
  union { float f; u32 i; } c; c.f = f;
  u32 u = c.i;
  return (u16)((u + 0x7FFFu + ((u >> 16) & 1u)) >> 16);  // RNE
}
__device__ __forceinline__ short8 pack8(float4 a, float4 b) {
  short8 r;
  r[0] = (short)f2b(a.x); r[1] = (short)f2b(a.y); r[2] = (short)f2b(a.z); r[3] = (short)f2b(a.w);
  r[4] = (short)f2b(b.x); r[5] = (short)f2b(b.y); r[6] = (short)f2b(b.z); r[7] = (short)f2b(b.w);
  return r;
}

// ---------------- embedding gather (f32 -> bf16) ----------------
__global__ void __launch_bounds__(256) gather_kernel(
    const int* __restrict__ x, const int* __restrict__ y,
    const float* __restrict__ emb_enc, const float* __restrict__ emb_dec,
    u16* __restrict__ ex, u16* __restrict__ ey)
{
  const int r = blockIdx.x, tid = threadIdx.x;
  if (r < B_ * S_) {                       // encoder row m = b*64+s
    int tok = x[r];
    float2 v = ((const float2*)(emb_enc + (size_t)tok * H_))[tid];
    ((u32*)(ex + (size_t)r * H_))[tid] = (u32)f2b(v.x) | ((u32)f2b(v.y) << 16);
  } else {                                 // decoder row m = t*16+b
    int m = r - B_ * S_;
    int t = m >> 4, b = m & 15;
    int tok = y[b * 64 + t];
    float2 v = ((const float2*)(emb_dec + (size_t)tok * H_))[tid];
    ((u32*)(ey + (size_t)m * H_))[tid] = (u32)f2b(v.x) | ((u32)f2b(v.y) << 16);
  }
}

// ---------------- bf16-MFMA GEMM: C = A @ B^T + bias ----------------
// A:[M,K] bf16, B:[N,K] f32 (converted to bf16 while staging), bias f32[N]
// MODE 0: C fp32 [M,N].
// MODE 1: C fp32 into d_out, row remap m=t*16+b -> (b*63+t)
// MODE 2: C = tanh(.) -> bf16 [M,N]
// SWAP 1: blockIdx.x indexes M-tiles, blockIdx.y indexes N-tiles (L2 locality:
//         dispatch-adjacent blocks share one B panel).
template <int MODE, int SWAP = 0>
__global__ void __launch_bounds__(256) gemm_bt(
    const u16* __restrict__ A, const float* __restrict__ Bm,
    const float* __restrict__ bias, void* __restrict__ Cout, int M, int N, int K)
{
  __shared__ u16 As[64 * 40];
  __shared__ u16 Bs[128 * 40];
  const int tid = threadIdx.x;
  const int wave = tid >> 6, lane = tid & 63;
  const int l15 = lane & 15, quad = lane >> 4;
  const int m0 = (SWAP ? blockIdx.x : blockIdx.y) * 64;
  const int n0 = (SWAP ? blockIdx.y : blockIdx.x) * 128;
  floatx4 acc[4][2] = {};

  for (int kk = 0; kk < K; kk += 32) {
    {
      int row = tid >> 2, ch = tid & 3;
      short8 v = {};
      int gm = m0 + row;
      if (gm < M) v = *(const short8*)(A + (size_t)gm * K + kk + ch * 8);
      *(short8*)(As + row * 40 + ch * 8) = v;
    }
#pragma unroll
    for (int i = 0; i < 4; ++i) {
      int idx2 = tid + i * 256;
      int row = idx2 >> 3, c4 = idx2 & 7;
      int gn = n0 + row;
      float4 w = *(const float4*)(Bm + (size_t)gn * K + kk + c4 * 4);
      uint2 p;
      p.x = (u32)f2b(w.x) | ((u32)f2b(w.y) << 16);
      p.y = (u32)f2b(w.z) | ((u32)f2b(w.w) << 16);
      *(uint2*)(Bs + row * 40 + c4 * 4) = p;
    }
    __syncthreads();
    short8 af[4], bfr[2];
#pragma unroll
    for (int mt = 0; mt < 4; ++mt)
      af[mt] = *(const short8*)(As + (mt * 16 + l15) * 40 + quad * 8);
#pragma unroll
    for (int nt = 0; nt < 2; ++nt)
      bfr[nt] = *(const short8*)(Bs + (wave * 32 + nt * 16 + l15) * 40 + quad * 8);
#pragma unroll
    for (int mt = 0; mt < 4; ++mt)
#pragma unroll
      for (int nt = 0; nt < 2; ++nt)
        acc[mt][nt] = __builtin_amdgcn_mfma_f32_16x16x32_bf16(af[mt], bfr[nt], acc[mt][nt], 0, 0, 0);
    __syncthreads();
  }
#pragma unroll
  for (int mt = 0; mt < 4; ++mt) {
#pragma unroll
    for (int nt = 0; nt < 2; ++nt) {
      int gn = n0 + wave * 32 + nt * 16 + l15;
      float bv = bias[gn];
#pragma unroll
      for (int r = 0; r < 4; ++r) {
        int gm = m0 + mt * 16 + quad * 4 + r;  // C/D: col=lane&15, row=quad*4+reg
        if (gm < M) {
          float v = acc[mt][nt][r] + bv;
          if (MODE == 0) {
            ((float*)Cout)[(size_t)gm * N + gn] = v;
          } else if (MODE == 1) {
            int tt = gm >> 4, bb = gm & 15;
            ((float*)Cout)[((size_t)bb * TD + tt) * V_ + gn] = v;
          } else {
            ((u16*)Cout)[(size_t)gm * N + gn] = f2b(tanhf(v));
          }
        }
      }
    }
  }
}

// ---------------- cooperative recurrence (GRU chain ONLY) ----------------
// 16 blocks x 384 threads; block k owns h-columns [32k, 32k+32).
// SLIDING-ARENA fence-free sync:
//   * h exchange lives in a 128-slot arena (16 KB/slot) inside d_out (dead
//     until the logits GEMM). Step s READS arena[s] with PLAIN dwordx4 loads
//     (addresses never touched this launch -> L2 miss -> fresh MALL fetch;
//     dispatch-begin acquire invalidated L2, so no cross-launch staleness),
//     and WRITES arena[s+1] with relaxed agent-scope atomic u32 stores
//     (land at MALL, visible to all XCDs, no wbl2 needed).
//   * Producer order: h' atomic stores -> s_waitcnt vmcnt(0) -> own signal
//     slot (waves 2 & 5 each own one of 32 slots; value = steps completed).
//   * Consumers poll all 32 slots (relaxed atomic loads) before each step.
//   * ZERO fences -> no per-phase L2 writeback/invalidate; gi stays L2-cached.
struct RecArgs {
  const float* gi_enc;   // [1024][1536]  row = b*64+s
  const float* gi_dec;   // [1008][1536]  row = t*16+b
  const float* Whe;      // [1536][512] raw W_hh_e
  const float* Whd;      // [1536][512] raw W_hh_d
  const float* bhe;      // [1536]
  const float* bhd;      // [1536]
  u16* eo;               // enc_out bf16 [16][64][512]
  u16* arena;            // [128][16][512] bf16 h arena (in d_out; [0] memset 0)
  u16* hcat;             // [1008][1024] bf16: cols 0..511 = h_t, 512..1023 = attn (later)
  int* bar;              // 32 signal slots (block*2 + half), stride 32 ints (128 B)
};

__device__ __forceinline__ void pollbar(const int* slots, int lane, int gen) {
  if (gen > 0) {
    while (__hip_atomic_load(slots + (lane & 31) * 32, __ATOMIC_RELAXED, __HIP_MEMORY_SCOPE_AGENT) < gen) {}
  }
  asm volatile("" ::: "memory");
}

// One GRU gate+update phase. astep = arena index of the INPUT h (global step).
template <int ISENC>
__device__ __forceinline__ void gate_phase(const RecArgs& a, int wave, int lane, int l15, int quad,
    int J, int step, int astep, const short8* wf, float bh, float* hreg,
    float (&lds_rz)[2][2][16][16], bool do_signal)
{
  const int sub = wave % 3, half = wave / 3;
  const int jc = J + half * 16 + l15;
  const float* gi = ISENC ? a.gi_enc : a.gi_dec;
  float giv[4];
#pragma unroll
  for (int r = 0; r < 4; ++r) {
    const int b = quad * 4 + r;
    const int row = ISENC ? (b * 64 + step) : (step * 16 + b);
    giv[r] = gi[(size_t)row * G3 + sub * 512 + jc];
  }
  const u16* hb = a.arena + (size_t)astep * 8192 + l15 * 512 + quad * 8;
  short8 af[16];
#pragma unroll
  for (int kk = 0; kk < 16; ++kk) af[kk] = *(const short8*)(hb + kk * 32);
  floatx4 acc = {0.f, 0.f, 0.f, 0.f};
#pragma unroll
  for (int kk = 0; kk < 16; ++kk)
    acc = __builtin_amdgcn_mfma_f32_16x16x32_bf16(af[kk], wf[(ISENC ? 0 : 16) + kk], acc, 0, 0, 0);
  if (sub < 2) {
#pragma unroll
    for (int r = 0; r < 4; ++r)
      lds_rz[sub][half][quad * 4 + r][l15] = acc[r] + bh + giv[r];
    __syncthreads();
  } else {
    __syncthreads();
#pragma unroll
    for (int r = 0; r < 4; ++r) {
      const int b = quad * 4 + r;
      const float rp = lds_rz[0][half][b][l15];
      const float zp = lds_rz[1][half][b][l15];
      const float rr = 1.f / (1.f + __expf(-rp));
      const float zz = 1.f / (1.f + __expf(-zp));
      const float nn = tanhf(giv[r] + rr * (acc[r] + bh));   // n = tanh(gi_n + r*(gh_n + bhh_n))
      const float hv = (1.f - zz) * nn + zz * hreg[r];
      hreg[r] = hv;
      const u16 h16 = f2b(hv);
      const u32 up = (u32)h16 | ((u32)(u16)__shfl_xor((int)h16, 1) << 16);
      if (!(lane & 1)) {
        __hip_atomic_store((u32*)(a.arena + (size_t)(astep + 1) * 8192 + b * 512 + jc), up,
                           __ATOMIC_RELAXED, __HIP_MEMORY_SCOPE_AGENT);
        if (ISENC) *(u32*)(a.eo + ((size_t)(b * 64 + step)) * 512 + jc) = up;
        else       *(u32*)(a.hcat + ((size_t)(step * 16 + b)) * 1024 + jc) = up;
      }
    }
    if (do_signal) {
      asm volatile("s_waitcnt vmcnt(0)" ::: "memory");     // h' stores at MALL
      if (lane == 0)
        __hip_atomic_store(a.bar + ((int)blockIdx.x * 2 + half) * 32, astep + 1,
                           __ATOMIC_RELAXED, __HIP_MEMORY_SCOPE_AGENT);
    }
  }
}

__global__ void __launch_bounds__(384) rec_kernel(RecArgs a) {
  __shared__ float lds_rz[2][2][16][16];
  const int tid = threadIdx.x;
  const int wave = tid >> 6, lane = tid & 63;
  const int l15 = lane & 15, quad = lane >> 4;
  const int J = blockIdx.x * 32;
  const int sub = wave % 3, half = wave / 3;

  // ---- one-time: stage W_hh gate fragments into registers (bf16) ----
  short8 wf[32];
  const int row = sub * 512 + J + half * 16 + l15;   // gate row of W_hh
  const float* pe = a.Whe + (size_t)row * 512 + quad * 8;
  const float* pd = a.Whd + (size_t)row * 512 + quad * 8;
#pragma unroll
  for (int kk = 0; kk < 16; ++kk) {
    wf[kk]      = pack8(*(const float4*)(pe + kk * 32), *(const float4*)(pe + kk * 32 + 4));
    wf[16 + kk] = pack8(*(const float4*)(pd + kk * 32), *(const float4*)(pd + kk * 32 + 4));
  }
  const int jc = J + half * 16 + l15;
  const float bhe = a.bhe[sub * 512 + jc];
  const float bhd = a.bhd[sub * 512 + jc];

  float hreg[4] = {0.f, 0.f, 0.f, 0.f};

  // arena[0] = h_0 = zeros (host-side memset; visible via dispatch acquire).
  // Slot semantics: value g  <=>  arena[g] is ready. Slots memset to 0.

  // ---- encoder: steps 0..63, arena 0->1 .. 63->64 ----
  for (int s = 0; s < S_; ++s) {
    pollbar(a.bar, lane, s);
    gate_phase<1>(a, wave, lane, l15, quad, J, s, s, wf, bhe, hreg, lds_rz, true);
  }
  // ---- decoder: steps 0..62, arena 64->65 .. 126->127 (no final signal) ----
  for (int t = 0; t < TD; ++t) {
    pollbar(a.bar, lane, 64 + t);
    gate_phase<0>(a, wave, lane, l15, quad, J, t, 64 + t, wf, bhd, hreg, lds_rz, t < TD - 1);
  }
}

// ---------------- attention, hoisted out of the loop ----------------
__global__ void __launch_bounds__(512) attn_kernel(
    const u16* __restrict__ eo16, u16* __restrict__ hcat)
{
  __shared__ float sc[64][9];
  __shared__ float wts[64];
  const int m = blockIdx.x, b = m & 15;
  const int tid = threadIdx.x;
  const u16* eo = eo16 + (size_t)b * 64 * 512;
  const u16* h = hcat + (size_t)m * 1024;
  {
    const int s = tid >> 3, q = tid & 7;
    const u16* ep = eo + s * 512 + q * 64;
    const u16* hp = h + q * 64;
    float acc = 0.f;
#pragma unroll
    for (int u = 0; u < 8; ++u) {
      short8 e8 = *(const short8*)(ep + u * 8);
      short8 h8 = *(const short8*)(hp + u * 8);
#pragma unroll
      for (int i = 0; i < 8; ++i) acc += b2f((u16)e8[i]) * b2f((u16)h8[i]);
    }
    sc[s][q] = acc;
  }
  __syncthreads();
  if (tid < 64) {
    float v = 0.f;
#pragma unroll
    for (int u = 0; u < 8; ++u) v += sc[tid][u];
    float mx = v;
#pragma unroll
    for (int d = 1; d < 64; d <<= 1) mx = fmaxf(mx, __shfl_xor(mx, d));
    float e = __expf(v - mx);
    float sum = e;
#pragma unroll
    for (int d = 1; d < 64; d <<= 1) sum += __shfl_xor(sum, d);
    wts[tid] = e / sum;
  }
  __syncthreads();
  {
    const int j = tid;
    float acc = 0.f;
#pragma unroll 8
    for (int s2 = 0; s2 < 64; ++s2) acc += wts[s2] * b2f(eo[s2 * 512 + j]);
    hcat[(size_t)m * 1024 + 512 + j] = f2b(acc);
  }
}

// ---------------- loss: single-pass online softmax over f32 logits ----------------
__global__ void __launch_bounds__(256) loss_rows_kernel(
    const float* __restrict__ logits, const int* __restrict__ y, float* __restrict__ nll)
{
  __shared__ float wm[4], ws_[4];
  const int m = blockIdx.x;               // m = t*16+b
  const int t = m >> 4, b = m & 15;
  const float* row = logits + ((size_t)b * TD + t) * V_;
  const int tid = threadIdx.x;
  const int lane = tid & 63, wave = tid >> 6;

  float mx = -1e30f, sum = 0.f;
  for (int c = tid; c < 8000; c += 256) {
    float4 v = ((const float4*)row)[c];
    float m4 = fmaxf(fmaxf(v.x, v.y), fmaxf(v.z, v.w));
    if (m4 > mx) { sum *= __expf(mx - m4); mx = m4; }
    sum += __expf(v.x - mx) + __expf(v.y - mx) + __expf(v.z - mx) + __expf(v.w - mx);
  }
#pragma unroll
  for (int d = 1; d < 64; d <<= 1) {
    float om = __shfl_xor(mx, d), os = __shfl_xor(sum, d);
    float nm = fmaxf(mx, om);
    sum = sum * __expf(mx - nm) + os * __expf(om - nm);
    mx = nm;
  }
  if (lane == 0) { wm[wave] = mx; ws_[wave] = sum; }
  __syncthreads();
  if (tid == 0) {
    float M = wm[0], S = ws_[0];
#pragma unroll
    for (int u = 1; u < 4; ++u) {
      float nm = fmaxf(M, wm[u]);
      S = S * __expf(M - nm) + ws_[u] * __expf(wm[u] - nm);
      M = nm;
    }
    int tok = y[b * 64 + t + 1];
    nll[m] = M + logf(S) - row[tok];
  }
}

__global__ void __launch_bounds__(256) loss_final_kernel(const float* __restrict__ nll, float* __restrict__ out) {
  __shared__ float wred[4];
  const int tid = threadIdx.x;
  float s = 0.f;
  for (int i = tid; i < MROWS; i += 256) s += nll[i];
#pragma unroll
  for (int d = 1; d < 64; d <<= 1) s += __shfl_xor(s, d);
  if ((tid & 63) == 0) wred[tid >> 6] = s;
  __syncthreads();
  if (tid == 0) out[0] = (wred[0] + wred[1] + wred[2] + wred[3]) / 1008.f;
}

// ---------------- launch ----------------
extern "C" void kernel_launch(void* const* d_in, const int* in_sizes, int n_in,
                              void* d_out, int out_size, void* d_ws, size_t ws_size,
                              hipStream_t stream)
{
  const int*   x       = (const int*)d_in[0];
  const int*   y       = (const int*)d_in[1];
  const float* emb_enc = (const float*)d_in[2];
  const float* W_ih_e  = (const float*)d_in[3];
  const float* W_hh_e  = (const float*)d_in[4];
  const float* b_ih_e  = (const float*)d_in[5];
  const float* b_hh_e  = (const float*)d_in[6];
  const float* emb_dec = (const float*)d_in[7];
  const float* W_ih_d  = (const float*)d_in[8];
  const float* W_hh_d  = (const float*)d_in[9];
  const float* b_ih_d  = (const float*)d_in[10];
  const float* b_hh_d  = (const float*)d_in[11];
  const float* W_c     = (const float*)d_in[12];
  const float* b_c     = (const float*)d_in[13];
  const float* W_out   = (const float*)d_in[14];
  const float* b_out   = (const float*)d_in[15];

  // ws layout (16,687,040 B total — within the proven footprint)
  char* ws = (char*)d_ws;
  float* gi_enc = (float*)(ws + 0);           //  6,291,456
  float* gi_dec = (float*)(ws + 6291456);     //  6,193,152  -> 12,484,608
  u16* embx     = (u16*)(ws + 12484608);      //  1,048,576  -> 13,533,184 (dead after gi GEMMs)
  u16* emby     = (u16*)(ws + 13533184);      //  1,032,192  -> 14,565,376 (dead after gi GEMMs)
  u16* hcat     = (u16*)(ws + 12484608);      //  2,064,384  -> 14,548,992 (reuses embx/emby region)
  u16* Dm       = (u16*)(ws + 14565376);      //  1,032,192  -> 15,597,568
  u16* eo16     = (u16*)(ws + 15597568);      //  1,048,576  -> 16,646,144
  float* nll    = (float*)(ws + 16678912);    //      4,032  -> 16,682,944
  int* bar      = (int*)(ws + 16682944);      //      4,096  -> 16,687,040

  // h arena: 128 slots x 16 KB = 2 MB inside d_out (logits region, dead until
  // the logits GEMM overwrites it). arena[0] = h_0 = zeros.
  u16* arena = (u16*)d_out;

  hipMemsetAsync(bar, 0, 4096, stream);       // 32 signal slots (graph-capture safe)
  hipMemsetAsync(d_out, 0, 16384, stream);    // arena[0] = h_0 = 0

  gather_kernel<<<dim3(B_ * S_ + MROWS), dim3(256), 0, stream>>>(x, y, emb_enc, emb_dec, embx, emby);

  gemm_bt<0><<<dim3(12, 16), dim3(256), 0, stream>>>(embx, W_ih_e, b_ih_e, (void*)gi_enc, 1024, G3, 512);
  gemm_bt<0><<<dim3(12, 16), dim3(256), 0, stream>>>(emby, W_ih_d, b_ih_d, (void*)gi_dec, MROWS, G3, 512);

  RecArgs ra{gi_enc, gi_dec, W_hh_e, W_hh_d, b_hh_e, b_hh_d, eo16, arena, hcat, bar};
  rec_kernel<<<dim3(NBLK), dim3(384), 0, stream>>>(ra);

  attn_kernel<<<dim3(MROWS), dim3(512), 0, stream>>>(eo16, hcat);

  // Dm = tanh([h;attn] @ W_c^T + b_c)  (bf16 out)
  gemm_bt<2><<<dim3(4, 16), dim3(256), 0, stream>>>(hcat, W_c, b_c, (void*)Dm, MROWS, 512, 1024);

  // logits: SWAP grid (M-tiles fast) so dispatch-adjacent blocks share a W_out panel
  gemm_bt<1, 1><<<dim3(16, 250), dim3(256), 0, stream>>>(Dm, W_out, b_out, d_out, MROWS, V_, 512);
  loss_rows_kernel<<<dim3(MROWS), dim3(256), 0, stream>>>((const float*)d_out, y, nll);
  loss_final_kernel<<<dim3(1), dim3(256), 0, stream>>>(nll, ((float*)d_out) + (size_t)MROWS * V_);
}

// Round 9
// 1186.529 us; speedup vs baseline: 1.3428x; 1.0784x over previous
//
#include <hip/hip_runtime.h>

typedef unsigned short u16;
typedef unsigned int u32;
typedef __attribute__((ext_vector_type(8))) short short8;
typedef __attribute__((ext_vector_type(4))) float floatx4;

#define B_ 16
#define S_ 64
#define H_ 512
#define V_ 32000
#define G3 1536   // 3*H
#define TD 63     // T-1
#define MROWS 1008
#define NBLK 16   // rec_kernel blocks (one per 32-col slice of h)

// rec dynamic LDS layout: rz 4096 B | eoL 65536 B | hcL 64512 B
#define REC_LDS_BYTES (4096 + 65536 + 64512)

__device__ __forceinline__ float b2f(u16 u) {
  union { u32 i; float f; } c; c.i = ((u32)u) << 16; return c.f;
}
__device__ __forceinline__ u16 f2b(float f) {
  union { float f; u32 i; } c; c.f = f;
  u32 u = c.i;
  return (u16)((u + 0x7FFFu + ((u >> 16) & 1u)) >> 16);  // RNE
}
__device__ __forceinline__ short8 pack8(float4 a, float4 b) {
  short8 r;
  r[0] = (short)f2b(a.x); r[1] = (short)f2b(a.y); r[2] = (short)f2b(a.z); r[3] = (short)f2b(a.w);
  r[4] = (short)f2b(b.x); r[5] = (short)f2b(b.y); r[6] = (short)f2b(b.z); r[7] = (short)f2b(b.w);
  return r;
}

// ---------------- embedding gather (f32 -> bf16) ----------------
__global__ void __launch_bounds__(256) gather_kernel(
    const int* __restrict__ x, const int* __restrict__ y,
    const float* __restrict__ emb_enc, const float* __restrict__ emb_dec,
    u16* __restrict__ ex, u16* __restrict__ ey)
{
  const int r = blockIdx.x, tid = threadIdx.x;
  if (r < B_ * S_) {                       // encoder row m = b*64+s
    int tok = x[r];
    float2 v = ((const float2*)(emb_enc + (size_t)tok * H_))[tid];
    ((u32*)(ex + (size_t)r * H_))[tid] = (u32)f2b(v.x) | ((u32)f2b(v.y) << 16);
  } else {                                 // decoder row m = t*16+b
    int m = r - B_ * S_;
    int t = m >> 4, b = m & 15;
    int tok = y[b * 64 + t];
    float2 v = ((const float2*)(emb_dec + (size_t)tok * H_))[tid];
    ((u32*)(ey + (size_t)m * H_))[tid] = (u32)f2b(v.x) | ((u32)f2b(v.y) << 16);
  }
}

// ---------------- bf16-MFMA GEMM: C = A @ B^T + bias ----------------
// A:[M,K] bf16, B:[N,K] f32 (converted to bf16 while staging), bias f32[N]
// MODE 0: C fp32 [M,N].
// MODE 1: C fp32 into d_out, row remap m=t*16+b -> (b*63+t)
// MODE 2: C = tanh(.) -> bf16 [M,N]
// SWAP 0: grid (N/128, M/64).  SWAP 2: 1D XCD-swizzled grid (4096 blocks):
//   all 16 M-tiles of one N-panel land on ONE XCD (p = ph*8 + bid%8), so the
//   B panel is fetched from HBM once instead of 8x. Pads to 256 panels.
template <int MODE, int SWAP = 0>
__global__ void __launch_bounds__(256) gemm_bt(
    const u16* __restrict__ A, const float* __restrict__ Bm,
    const float* __restrict__ bias, void* __restrict__ Cout, int M, int N, int K)
{
  __shared__ u16 As[64 * 40];
  __shared__ u16 Bs[128 * 40];
  const int tid = threadIdx.x;
  const int wave = tid >> 6, lane = tid & 63;
  const int l15 = lane & 15, quad = lane >> 4;
  int m0, n0;
  if (SWAP == 2) {
    const int bid = blockIdx.x;
    const int xcd = bid & 7, w = bid >> 3;
    const int mt = w & 15, ph = w >> 4;          // ph in 0..31
    const int p = ph * 8 + xcd;                  // panel, same XCD for all mt
    if (p >= N / 128) return;
    m0 = mt * 64; n0 = p * 128;
  } else {
    m0 = blockIdx.y * 64; n0 = blockIdx.x * 128;
  }
  floatx4 acc[4][2] = {};

  for (int kk = 0; kk < K; kk += 32) {
    {
      int row = tid >> 2, ch = tid & 3;
      short8 v = {};
      int gm = m0 + row;
      if (gm < M) v = *(const short8*)(A + (size_t)gm * K + kk + ch * 8);
      *(short8*)(As + row * 40 + ch * 8) = v;
    }
#pragma unroll
    for (int i = 0; i < 4; ++i) {
      int idx2 = tid + i * 256;
      int row = idx2 >> 3, c4 = idx2 & 7;
      int gn = n0 + row;
      float4 w = *(const float4*)(Bm + (size_t)gn * K + kk + c4 * 4);
      uint2 p;
      p.x = (u32)f2b(w.x) | ((u32)f2b(w.y) << 16);
      p.y = (u32)f2b(w.z) | ((u32)f2b(w.w) << 16);
      *(uint2*)(Bs + row * 40 + c4 * 4) = p;
    }
    __syncthreads();
    short8 af[4], bfr[2];
#pragma unroll
    for (int mt = 0; mt < 4; ++mt)
      af[mt] = *(const short8*)(As + (mt * 16 + l15) * 40 + quad * 8);
#pragma unroll
    for (int nt = 0; nt < 2; ++nt)
      bfr[nt] = *(const short8*)(Bs + (wave * 32 + nt * 16 + l15) * 40 + quad * 8);
#pragma unroll
    for (int mt = 0; mt < 4; ++mt)
#pragma unroll
      for (int nt = 0; nt < 2; ++nt)
        acc[mt][nt] = __builtin_amdgcn_mfma_f32_16x16x32_bf16(af[mt], bfr[nt], acc[mt][nt], 0, 0, 0);
    __syncthreads();
  }
#pragma unroll
  for (int mt = 0; mt < 4; ++mt) {
#pragma unroll
    for (int nt = 0; nt < 2; ++nt) {
      int gn = n0 + wave * 32 + nt * 16 + l15;
      float bv = bias[gn];
#pragma unroll
      for (int r = 0; r < 4; ++r) {
        int gm = m0 + mt * 16 + quad * 4 + r;  // C/D: col=lane&15, row=quad*4+reg
        if (gm < M) {
          float v = acc[mt][nt][r] + bv;
          if (MODE == 0) {
            ((float*)Cout)[(size_t)gm * N + gn] = v;
          } else if (MODE == 1) {
            int tt = gm >> 4, bb = gm & 15;
            ((float*)Cout)[((size_t)bb * TD + tt) * V_ + gn] = v;
          } else {
            ((u16*)Cout)[(size_t)gm * N + gn] = f2b(tanhf(v));
          }
        }
      }
    }
  }
}

// ---------------- cooperative recurrence (GRU chain ONLY) ----------------
// 16 blocks x 384 threads; block k owns h-columns [32k, 32k+32).
// Sync: the PROVEN fenced barrier (r2/r5, 692 us). Delta vs r5: eo/hcat are
// staged in LDS during the loop and flushed to global ONCE at the end --
// per-phase global traffic is h' only (1 KB/block), so the release-fence
// drain + wbl2 writeback are lighter every phase.
struct RecArgs {
  const float* gi_enc;   // [1024][1536]  row = b*64+s
  const float* gi_dec;   // [1008][1536]  row = t*16+b
  const float* Whe;      // [1536][512] raw W_hh_e
  const float* Whd;      // [1536][512] raw W_hh_d
  const float* bhe;      // [1536]
  const float* bhd;      // [1536]
  u16* eo;               // enc_out bf16 [16][64][512]
  u16* ha;               // [2][16][512] bf16 h exchange
  u16* hcat;             // [1008][1024] bf16: cols 0..511 = h_t, 512..1023 = attn (later)
  int* bar;              // 16 arrival slots, 128B apart, generation-tagged
};

// PROVEN fenced barrier: release fence + slot store + 16-lane poll + acquire fence.
__device__ __forceinline__ void gridbar(int* slots, int gen) {
  __syncthreads();
  if (threadIdx.x < 16) {
    if (threadIdx.x == 0) {
      __builtin_amdgcn_fence(__ATOMIC_RELEASE, "agent");
      __hip_atomic_store(slots + (int)blockIdx.x * 32, gen, __ATOMIC_RELAXED, __HIP_MEMORY_SCOPE_AGENT);
    }
    while (__hip_atomic_load(slots + (int)threadIdx.x * 32, __ATOMIC_RELAXED, __HIP_MEMORY_SCOPE_AGENT) < gen) {}
    __builtin_amdgcn_fence(__ATOMIC_ACQUIRE, "agent");
  }
  __syncthreads();
}

typedef float rz_t[2][16][16];

// One GRU gate+update phase. p = read parity (reads ha[p], writes ha[p^1]).
// eo/hcat land in LDS (eoL/hcL, u32-packed pairs), flushed after the loop.
template <int ISENC>
__device__ __forceinline__ void gate_phase(const RecArgs& a, int wave, int lane, int l15, int quad,
    int J, int step, int p, const short8* wf, float bh, float* hreg,
    rz_t* lds_rz, u32* eoL, u32* hcL)
{
  const int sub = wave % 3, half = wave / 3;
  const int jc = J + half * 16 + l15;
  const float* gi = ISENC ? a.gi_enc : a.gi_dec;
  float giv[4];
#pragma unroll
  for (int r = 0; r < 4; ++r) {
    const int b = quad * 4 + r;
    const int row = ISENC ? (b * 64 + step) : (step * 16 + b);
    giv[r] = gi[(size_t)row * G3 + sub * 512 + jc];
  }
  const u16* hb = a.ha + p * 8192 + l15 * 512 + quad * 8;
  short8 af[16];
#pragma unroll
  for (int kk = 0; kk < 16; ++kk) af[kk] = *(const short8*)(hb + kk * 32);
  floatx4 acc = {0.f, 0.f, 0.f, 0.f};
#pragma unroll
  for (int kk = 0; kk < 16; ++kk)
    acc = __builtin_amdgcn_mfma_f32_16x16x32_bf16(af[kk], wf[(ISENC ? 0 : 16) + kk], acc, 0, 0, 0);
  if (sub < 2) {
#pragma unroll
    for (int r = 0; r < 4; ++r)
      lds_rz[sub][half][quad * 4 + r][l15] = acc[r] + bh + giv[r];
    __syncthreads();
  } else {
    __syncthreads();
    const int pn = p ^ 1;
#pragma unroll
    for (int r = 0; r < 4; ++r) {
      const int b = quad * 4 + r;
      const float rp = lds_rz[0][half][b][l15];
      const float zp = lds_rz[1][half][b][l15];
      const float rr = 1.f / (1.f + __expf(-rp));
      const float zz = 1.f / (1.f + __expf(-zp));
      const float nn = tanhf(giv[r] + rr * (acc[r] + bh));   // n = tanh(gi_n + r*(gh_n + bhh_n))
      const float hv = (1.f - zz) * nn + zz * hreg[r];
      hreg[r] = hv;
      const u16 h16 = f2b(hv);
      const u32 up = (u32)h16 | ((u32)(u16)__shfl_xor((int)h16, 1) << 16);
      if (!(lane & 1)) {
        *(u32*)(a.ha + pn * 8192 + b * 512 + jc) = up;       // cross-block h'
        const int c2 = half * 8 + (l15 >> 1);
        if (ISENC) eoL[(b * 64 + step) * 16 + c2] = up;      // LDS staging
        else       hcL[(step * 16 + b) * 16 + c2] = up;
      }
    }
  }
}

__global__ void __launch_bounds__(384) rec_kernel(RecArgs a) {
  extern __shared__ char smem[];
  rz_t* lds_rz = (rz_t*)smem;                       //  4,096 B  [2][2][16][16] f32
  u32* eoL = (u32*)(smem + 4096);                   // 65,536 B  [16*64][16] u32
  u32* hcL = (u32*)(smem + 4096 + 65536);           // 64,512 B  [63*16][16] u32

  const int tid = threadIdx.x;
  const int wave = tid >> 6, lane = tid & 63;
  const int l15 = lane & 15, quad = lane >> 4;
  const int J = blockIdx.x * 32;
  const int sub = wave % 3, half = wave / 3;

  // ---- one-time: stage W_hh gate fragments into registers (bf16) ----
  short8 wf[32];
  const int row = sub * 512 + J + half * 16 + l15;   // gate row of W_hh
  const float* pe = a.Whe + (size_t)row * 512 + quad * 8;
  const float* pd = a.Whd + (size_t)row * 512 + quad * 8;
#pragma unroll
  for (int kk = 0; kk < 16; ++kk) {
    wf[kk]      = pack8(*(const float4*)(pe + kk * 32), *(const float4*)(pe + kk * 32 + 4));
    wf[16 + kk] = pack8(*(const float4*)(pd + kk * 32), *(const float4*)(pd + kk * 32 + 4));
  }
  const int jc = J + half * 16 + l15;
  const float bhe = a.bhe[sub * 512 + jc];
  const float bhd = a.bhd[sub * 512 + jc];

  float hreg[4] = {0.f, 0.f, 0.f, 0.f};
  // zero-init h buffer 0 (own columns; the 16 blocks cover all 512)
  if (sub == 2) {
#pragma unroll
    for (int r = 0; r < 4; ++r)
      a.ha[(quad * 4 + r) * 512 + jc] = 0;
  }
  int gen = 0;
  gridbar(a.bar, ++gen);

  // ---- encoder: 1 barrier / step ----
  for (int s = 0; s < S_; ++s) {
    gate_phase<1>(a, wave, lane, l15, quad, J, s, s & 1, wf, bhe, hreg, lds_rz, eoL, hcL);
    gridbar(a.bar, ++gen);
  }
  // ---- decoder: 1 barrier / step, none after the last ----
  for (int t = 0; t < TD; ++t) {
    gate_phase<0>(a, wave, lane, l15, quad, J, t, t & 1, wf, bhd, hreg, lds_rz, eoL, hcL);
    if (t < TD - 1) gridbar(a.bar, ++gen);
  }

  // ---- flush eo/hcat LDS stages to global (off the phase critical path) ----
  __syncthreads();
  for (int i = tid; i < 16 * 64 * 16; i += 384) {
    const int c2 = i & 15, rs = i >> 4;              // rs = b*64+s
    *(u32*)(a.eo + (size_t)rs * 512 + J + c2 * 2) = eoL[i];
  }
  for (int i = tid; i < 63 * 16 * 16; i += 384) {
    const int c2 = i & 15, rt = i >> 4;              // rt = t*16+b
    *(u32*)(a.hcat + (size_t)rt * 1024 + J + c2 * 2) = hcL[i];
  }
}

// ---------------- attention, hoisted out of the loop ----------------
__global__ void __launch_bounds__(512) attn_kernel(
    const u16* __restrict__ eo16, u16* __restrict__ hcat)
{
  __shared__ float sc[64][9];
  __shared__ float wts[64];
  const int m = blockIdx.x, b = m & 15;
  const int tid = threadIdx.x;
  const u16* eo = eo16 + (size_t)b * 64 * 512;
  const u16* h = hcat + (size_t)m * 1024;
  {
    const int s = tid >> 3, q = tid & 7;
    const u16* ep = eo + s * 512 + q * 64;
    const u16* hp = h + q * 64;
    float acc = 0.f;
#pragma unroll
    for (int u = 0; u < 8; ++u) {
      short8 e8 = *(const short8*)(ep + u * 8);
      short8 h8 = *(const short8*)(hp + u * 8);
#pragma unroll
      for (int i = 0; i < 8; ++i) acc += b2f((u16)e8[i]) * b2f((u16)h8[i]);
    }
    sc[s][q] = acc;
  }
  __syncthreads();
  if (tid < 64) {
    float v = 0.f;
#pragma unroll
    for (int u = 0; u < 8; ++u) v += sc[tid][u];
    float mx = v;
#pragma unroll
    for (int d = 1; d < 64; d <<= 1) mx = fmaxf(mx, __shfl_xor(mx, d));
    float e = __expf(v - mx);
    float sum = e;
#pragma unroll
    for (int d = 1; d < 64; d <<= 1) sum += __shfl_xor(sum, d);
    wts[tid] = e / sum;
  }
  __syncthreads();
  {
    const int j = tid;
    float acc = 0.f;
#pragma unroll 8
    for (int s2 = 0; s2 < 64; ++s2) acc += wts[s2] * b2f(eo[s2 * 512 + j]);
    hcat[(size_t)m * 1024 + 512 + j] = f2b(acc);
  }
}

// ---------------- loss: single-pass online softmax over f32 logits ----------------
__global__ void __launch_bounds__(256) loss_rows_kernel(
    const float* __restrict__ logits, const int* __restrict__ y, float* __restrict__ nll)
{
  __shared__ float wm[4], ws_[4];
  const int m = blockIdx.x;               // m = t*16+b
  const int t = m >> 4, b = m & 15;
  const float* row = logits + ((size_t)b * TD + t) * V_;
  const int tid = threadIdx.x;
  const int lane = tid & 63, wave = tid >> 6;

  float mx = -1e30f, sum = 0.f;
  for (int c = tid; c < 8000; c += 256) {
    float4 v = ((const float4*)row)[c];
    float m4 = fmaxf(fmaxf(v.x, v.y), fmaxf(v.z, v.w));
    if (m4 > mx) { sum *= __expf(mx - m4); mx = m4; }
    sum += __expf(v.x - mx) + __expf(v.y - mx) + __expf(v.z - mx) + __expf(v.w - mx);
  }
#pragma unroll
  for (int d = 1; d < 64; d <<= 1) {
    float om = __shfl_xor(mx, d), os = __shfl_xor(sum, d);
    float nm = fmaxf(mx, om);
    sum = sum * __expf(mx - nm) + os * __expf(om - nm);
    mx = nm;
  }
  if (lane == 0) { wm[wave] = mx; ws_[wave] = sum; }
  __syncthreads();
  if (tid == 0) {
    float M = wm[0], S = ws_[0];
#pragma unroll
    for (int u = 1; u < 4; ++u) {
      float nm = fmaxf(M, wm[u]);
      S = S * __expf(M - nm) + ws_[u] * __expf(wm[u] - nm);
      M = nm;
    }
    int tok = y[b * 64 + t + 1];
    nll[m] = M + logf(S) - row[tok];
  }
}

__global__ void __launch_bounds__(256) loss_final_kernel(const float* __restrict__ nll, float* __restrict__ out) {
  __shared__ float wred[4];
  const int tid = threadIdx.x;
  float s = 0.f;
  for (int i = tid; i < MROWS; i += 256) s += nll[i];
#pragma unroll
  for (int d = 1; d < 64; d <<= 1) s += __shfl_xor(s, d);
  if ((tid & 63) == 0) wred[tid >> 6] = s;
  __syncthreads();
  if (tid == 0) out[0] = (wred[0] + wred[1] + wred[2] + wred[3]) / 1008.f;
}

// ---------------- launch ----------------
extern "C" void kernel_launch(void* const* d_in, const int* in_sizes, int n_in,
                              void* d_out, int out_size, void* d_ws, size_t ws_size,
                              hipStream_t stream)
{
  const int*   x       = (const int*)d_in[0];
  const int*   y       = (const int*)d_in[1];
  const float* emb_enc = (const float*)d_in[2];
  const float* W_ih_e  = (const float*)d_in[3];
  const float* W_hh_e  = (const float*)d_in[4];
  const float* b_ih_e  = (const float*)d_in[5];
  const float* b_hh_e  = (const float*)d_in[6];
  const float* emb_dec = (const float*)d_in[7];
  const float* W_ih_d  = (const float*)d_in[8];
  const float* W_hh_d  = (const float*)d_in[9];
  const float* b_ih_d  = (const float*)d_in[10];
  const float* b_hh_d  = (const float*)d_in[11];
  const float* W_c     = (const float*)d_in[12];
  const float* b_c     = (const float*)d_in[13];
  const float* W_out   = (const float*)d_in[14];
  const float* b_out   = (const float*)d_in[15];

  // ws layout (16,684,992 B total — within the proven footprint)
  char* ws = (char*)d_ws;
  float* gi_enc = (float*)(ws + 0);           //  6,291,456
  float* gi_dec = (float*)(ws + 6291456);     //  6,193,152  -> 12,484,608
  u16* embx     = (u16*)(ws + 12484608);      //  1,048,576  -> 13,533,184 (dead after gi GEMMs)
  u16* emby     = (u16*)(ws + 13533184);      //  1,032,192  -> 14,565,376 (dead after gi GEMMs)
  u16* hcat     = (u16*)(ws + 12484608);      //  2,064,384  -> 14,548,992 (reuses embx/emby region)
  u16* Dm       = (u16*)(ws + 14565376);      //  1,032,192  -> 15,597,568
  u16* eo16     = (u16*)(ws + 15597568);      //  1,048,576  -> 16,646,144
  u16* ha16     = (u16*)(ws + 16646144);      //     32,768  -> 16,678,912
  float* nll    = (float*)(ws + 16678912);    //      4,032  -> 16,682,944
  int* bar      = (int*)(ws + 16682944);      //      2,048  -> 16,684,992

  hipMemsetAsync(bar, 0, 2048, stream);       // barrier generation slots (graph-capture safe)

  // allow 131 KB dynamic LDS for rec_kernel (gfx950: 160 KB/CU)
  static bool attr_set = false;
  if (!attr_set) {
    hipFuncSetAttribute((const void*)rec_kernel,
                        hipFuncAttributeMaxDynamicSharedMemorySize, REC_LDS_BYTES);
    attr_set = true;
  }

  gather_kernel<<<dim3(B_ * S_ + MROWS), dim3(256), 0, stream>>>(x, y, emb_enc, emb_dec, embx, emby);

  gemm_bt<0><<<dim3(12, 16), dim3(256), 0, stream>>>(embx, W_ih_e, b_ih_e, (void*)gi_enc, 1024, G3, 512);
  gemm_bt<0><<<dim3(12, 16), dim3(256), 0, stream>>>(emby, W_ih_d, b_ih_d, (void*)gi_dec, MROWS, G3, 512);

  RecArgs ra{gi_enc, gi_dec, W_hh_e, W_hh_d, b_hh_e, b_hh_d, eo16, ha16, hcat, bar};
  rec_kernel<<<dim3(NBLK), dim3(384), REC_LDS_BYTES, stream>>>(ra);

  attn_kernel<<<dim3(MROWS), dim3(512), 0, stream>>>(eo16, hcat);

  // Dm = tanh([h;attn] @ W_c^T + b_c)  (bf16 out)
  gemm_bt<2><<<dim3(4, 16), dim3(256), 0, stream>>>(hcat, W_c, b_c, (void*)Dm, MROWS, 512, 1024);

  // logits: XCD-swizzled 1D grid — one XCD owns all 16 M-tiles of each W_out panel
  gemm_bt<1, 2><<<dim3(4096), dim3(256), 0, stream>>>(Dm, W_out, b_out, d_out, MROWS, V_, 512);
  loss_rows_kernel<<<dim3(MROWS), dim3(256), 0, stream>>>((const float*)d_out, y, nll);
  loss_final_kernel<<<dim3(1), dim3(256), 0, stream>>>(nll, ((float*)d_out) + (size_t)MROWS * V_);
}